// Round 6
// baseline (325.732 us; speedup 1.0000x reference)
//
#include <hip/hip_runtime.h>
#include <math.h>

typedef __attribute__((ext_vector_type(2))) float f32x2;

#define MAX_DELAY 128
#define INPUT 64
#define HIDDEN 128
#define HALF 64
#define OUT 64
#define BATCH 32
#define T 128
#define OUT_LEN 64
#define NTHR 512

static __device__ __forceinline__ f32x2 splat2(float v) { f32x2 r; r.x = v; r.y = v; return r; }

// DPP cross-lane (1-cycle VALU).
template <int CTRL>
static __device__ __forceinline__ float dpp_movf(float v) {
    return __int_as_float(__builtin_amdgcn_update_dpp(
        0, __float_as_int(v), CTRL, 0xF, 0xF, true));
}
#define DPP_XOR1 0xB1  // quad_perm [1,0,3,2]
#define DPP_XOR2 0x4E  // quad_perm [2,3,0,1]
#define DPP_ROT1 0x39  // quad_perm [1,2,3,0] (lane i <- i+1 mod 4)
#define DPP_MIR8 0x141 // row_half_mirror

// R5 structure + cross-barrier software pipelining:
//   Phase A (B1->B2): msg matvec  ||  DEFERRED deep blend of step i-1
//                     (register-only ALU fills the s_v ds_read latency)
//   Phase B (B2->B3): h1 matvec; stage next x slice
//   Phase C (B3->B1): tau/mem matvec; head-only blend (d=0); head publish;
//                     decode out-projection (fills s_h1 read latency)
// Startup is branch-free: mem_p=0 makes the first deferred blend a pure
// shift of the all-zero buffer.
__global__ __launch_bounds__(NTHR, 2)
void delayrnn_kernel(
    const float* __restrict__ x,        // (B, T, INPUT)
    const int*   __restrict__ lengths,  // (B)
    const float* __restrict__ Wm,       // (INPUT+HIDDEN, HIDDEN)
    const float* __restrict__ bm,       // (HIDDEN)
    const float* __restrict__ W1,       // (HIDDEN, HALF)
    const float* __restrict__ b1,       // (HALF)
    const float* __restrict__ W2,       // (HALF, 2*HIDDEN)
    const float* __restrict__ b2,       // (2*HIDDEN)
    const float* __restrict__ Wo,       // (HIDDEN, OUT)
    const float* __restrict__ bo,       // (OUT)
    float* __restrict__ out)            // (B, OUT_LEN, OUT)
{
    const int b   = blockIdx.x;
    const int tid = threadIdx.x;
    const int len = lengths[b];
    const int total = len + OUT_LEN;

    const int h  = tid >> 2, q  = tid & 3;   // channel quad
    const int qq = q & 1,    qh = q >> 1;    // tau/mem roles
    const int k1 = tid >> 3, r1 = tid & 7;   // h1 groups
    const int co = tid >> 3, ro = tid & 7;   // out-proj groups

    // ---- weights -> registers ----
    f32x2 wm2[24];
#pragma unroll
    for (int j = 0; j < 24; ++j) {
        wm2[j].x = Wm[(q * 48 + 2 * j)     * HIDDEN + h];
        wm2[j].y = Wm[(q * 48 + 2 * j + 1) * HIDDEN + h];
    }
    f32x2 w12[8];
#pragma unroll
    for (int j = 0; j < 8; ++j) {
        w12[j].x = W1[(r1 * 16 + 2 * j)     * HALF + k1];
        w12[j].y = W1[(r1 * 16 + 2 * j + 1) * HALF + k1];
    }
    const int c2 = h + 128 * qh;
    f32x2 w22[16];
#pragma unroll
    for (int j = 0; j < 16; ++j) {
        w22[j].x = W2[(qq * 32 + 2 * j)     * (2 * HIDDEN) + c2];
        w22[j].y = W2[(qq * 32 + 2 * j + 1) * (2 * HIDDEN) + c2];
    }
    f32x2 wo2[8];
#pragma unroll
    for (int j = 0; j < 8; ++j) {
        wo2[j].x = Wo[(ro * 16 + 2 * j)     * OUT + co];
        wo2[j].y = Wo[(ro * 16 + 2 * j + 1) * OUT + co];
    }
    const float bm_r = bm[h];
    const float b1_r = b1[k1];
    const float b2_r = b2[c2];
    const float bo_r = bo[co];

    float buf[32];
#pragma unroll
    for (int d = 0; d < 32; ++d) buf[d] = 0.f;

    __shared__ float s_x[T * INPUT];
    __shared__ float s_v[INPUT + HIDDEN];
    __shared__ float s_msg[HIDDEN];
    __shared__ float s_h1[HALF];

    for (int idx = tid; idx < T * INPUT; idx += NTHR)
        s_x[idx] = x[b * T * INPUT + idx];
    if (tid < INPUT) s_v[tid] = (0 < len) ? x[b * T * INPUT + tid] : 0.f;
    if (tid >= INPUT && tid < INPUT + HIDDEN) s_v[tid] = 0.f;
    __syncthreads();                                      // B1 (iter 0)

    const float ivb = (float)q * 0.25f;

    // pipeline registers (step i-1 blend params); zeros = no-op blend
    float msg_p = 0.f, tau_p = 0.f, mem_p = 0.f, head_old = 0.f;

    for (int i = 0; i < total; ++i) {
        // ================= Phase A =================
        // deferred deep blend of step i-1 (d = 1..31, register-only; the
        // scheduler hoists the msg matvec's ds_reads above this ALU)
        {
            float tail_in = dpp_movf<DPP_ROT1>(head_old); // neighbor's pre-blend head
            if (q == 3) tail_in = 0.f;
            const float taup = tau_p - ivb;
            const f32x2 tau2 = splat2(taup);
            const f32x2 mem2 = splat2(mem_p);
            const f32x2 m2m  = splat2(-2.f * mem_p);
            const f32x2 msg2 = splat2(msg_p);
#pragma unroll
            for (int mp = 0; mp < 15; ++mp) {
                const int d = 2 * mp + 1;                 // 1,3,..,29
                f32x2 nb; nb.x = buf[d + 1]; nb.y = buf[d + 2];
                f32x2 t;
                t.x = tau2.x - (float)d       * (1.f / MAX_DELAY);
                t.y = tau2.y - (float)(d + 1) * (1.f / MAX_DELAY);
                f32x2 a  = __builtin_elementwise_max(t, -t);
                f32x2 f1 = a * mem2 + m2m;
                f32x2 iw = a * f1 + mem2;
                f32x2 nv = iw * (msg2 - nb) + nb;
                buf[d] = nv.x; buf[d + 1] = nv.y;
            }
            {   // d = 31 (tail from neighbor's saved old head)
                const float t31 = taup - 31.f * (1.f / MAX_DELAY);
                const float a   = fabsf(t31);
                const float iw  = a * (a * mem_p - 2.f * mem_p) + mem_p;
                buf[31] = iw * (msg_p - tail_in) + tail_in;
            }
        }
        // msg matvec
        const f32x2* v2 = (const f32x2*)(s_v + q * 48);
        f32x2 a0 = splat2(0.f), a1 = splat2(0.f), a2 = splat2(0.f), a3 = splat2(0.f);
#pragma unroll
        for (int j = 0; j < 24; j += 4) {
            a0 += wm2[j] * v2[j];         a1 += wm2[j + 1] * v2[j + 1];
            a2 += wm2[j + 2] * v2[j + 2]; a3 += wm2[j + 3] * v2[j + 3];
        }
        f32x2 aa = (a0 + a1) + (a2 + a3);
        float p = aa.x + aa.y;
        p += dpp_movf<DPP_XOR1>(p);
        p += dpp_movf<DPP_XOR2>(p);
        const float z   = p + bm_r;
        const float e2  = __expf(2.f * z);
        const float msg = 1.f - 2.f * __builtin_amdgcn_rcpf(e2 + 1.f);
        if (q == 0) s_msg[h] = msg;
        __syncthreads();                                  // B2

        // ================= Phase B =================
        const f32x2* m2 = (const f32x2*)(s_msg + r1 * 16);
        f32x2 c0 = splat2(0.f), c1 = splat2(0.f);
#pragma unroll
        for (int j = 0; j < 8; j += 2) { c0 += w12[j] * m2[j]; c1 += w12[j + 1] * m2[j + 1]; }
        f32x2 cc = c0 + c1;
        float p1 = cc.x + cc.y;
        p1 += dpp_movf<DPP_XOR1>(p1);
        p1 += dpp_movf<DPP_XOR2>(p1);
        p1 += dpp_movf<DPP_MIR8>(p1);
        if (r1 == 0) s_h1[k1] = fmaxf(p1 + b1_r, 0.f);
        // stage next x slice (read by phase A of i+1; >= 1 barrier away)
        if (tid < INPUT) {
            const int nx = i + 1;
            s_v[tid] = (nx < len) ? s_x[nx * INPUT + tid] : 0.f;
        }
        __syncthreads();                                  // B3

        // ================= Phase C =================
        // tau/mem (s_h1 reads; out-proj below fills the latency)
        const f32x2* h2 = (const f32x2*)(s_h1 + qq * 32);
        f32x2 t0 = splat2(0.f), t1 = splat2(0.f);
#pragma unroll
        for (int j = 0; j < 16; j += 2) { t0 += w22[j] * h2[j]; t1 += w22[j + 1] * h2[j + 1]; }

        // decode out-projection (independent of tau; fills s_h1 wait)
        if (i >= len) {
            const f32x2* mo2 = (const f32x2*)(s_msg + ro * 16);
            f32x2 o0 = splat2(0.f), o1 = splat2(0.f);
#pragma unroll
            for (int j = 0; j < 8; j += 2) { o0 += wo2[j] * mo2[j]; o1 += wo2[j + 1] * mo2[j + 1]; }
            f32x2 oo = o0 + o1;
            float po = oo.x + oo.y;
            po += dpp_movf<DPP_XOR1>(po);
            po += dpp_movf<DPP_XOR2>(po);
            po += dpp_movf<DPP_MIR8>(po);
            if (ro == 0) out[(b * OUT_LEN + (i - len)) * OUT + co] = po + bo_r;
        }

        f32x2 tt = t0 + t1;
        float pt = tt.x + tt.y;
        pt += dpp_movf<DPP_XOR1>(pt);
        const float own = __builtin_amdgcn_rcpf(1.f + __expf(-(pt + b2_r)));
        const float oth = dpp_movf<DPP_XOR2>(own);
        const float tau_r = qh ? oth : own;
        const float mem_r = qh ? own : oth;

        // head-only blend (d = 0 of this lane's slice) + publish
        head_old = buf[0];                                // pre-blend head (tail source)
        {
            const float t0h = tau_r - ivb;
            const float a   = fabsf(t0h);
            const float iw  = a * (a * mem_r - 2.f * mem_r) + mem_r;
            const float nb  = buf[1];                     // post-blend-(i-1)
            buf[0] = iw * (msg - nb) + nb;
        }
        if (q == 0) s_v[INPUT + h] = buf[0];

        msg_p = msg; tau_p = tau_r; mem_p = mem_r;
        __syncthreads();                                  // B1 (next iter)
    }
}

extern "C" void kernel_launch(void* const* d_in, const int* in_sizes, int n_in,
                              void* d_out, int out_size, void* d_ws, size_t ws_size,
                              hipStream_t stream) {
    const float* x       = (const float*)d_in[0];
    const int*   lengths = (const int*)  d_in[1];
    // d_in[2] = out_lengths scalar (compile-time 64)
    const float* Wm = (const float*)d_in[3];
    const float* bm = (const float*)d_in[4];
    const float* W1 = (const float*)d_in[5];
    const float* b1 = (const float*)d_in[6];
    const float* W2 = (const float*)d_in[7];
    const float* b2 = (const float*)d_in[8];
    const float* Wo = (const float*)d_in[9];
    const float* bo = (const float*)d_in[10];
    float* out = (float*)d_out;

    delayrnn_kernel<<<BATCH, NTHR, 0, stream>>>(
        x, lengths, Wm, bm, W1, b1, W2, b2, Wo, bo, out);
}